// Round 5
// baseline (777.861 us; speedup 1.0000x reference)
//
#include <hip/hip_runtime.h>

// GCN 3-layer: x -> GCNConv(W1)+BN+ReLU -> GCNConv(W2)+BN+ReLU -> GCNConv(W3)
// Dest-sorted CSR built once per launch (1 u64 atomic/edge gives counts,
// weighted degree, and in-bucket rank -> atomic-free fill).
// Aggregation: XCD-affine feature sharding. F split into 8 chunks; chunk =
// blockIdx.x & 7 so (under round-robin block->XCD dispatch) each XCD gathers
// only from a 50k x 48B slice (2.4MB < 4MB per-XCD L2). One thread owns a
// whole chunk of one node -> contiguous 48B gather per edge, 8x less ep
// redundancy.

constexpr float BN_EPS = 1e-5f;
constexpr float FIXED_SCALE = 33554432.0f;        // 2^25
constexpr float INV_FIXED_SCALE = 1.0f / 33554432.0f;

__device__ inline float4 f4fma(float s, float4 a, float4 b) {
    return make_float4(fmaf(s, a.x, b.x), fmaf(s, a.y, b.y),
                       fmaf(s, a.z, b.z), fmaf(s, a.w, b.w));
}

// ---------------- graph build ----------------

__global__ void k_init(unsigned long long* packed, int n) {
    int i = blockIdx.x * blockDim.x + threadIdx.x;
    if (i < n) packed[i] = 0ull;
}

// one u64 atomic per edge; old>>32 = rank of this edge within its dest bucket
__global__ void k_deg(const int* __restrict__ col_idx, const float* __restrict__ ew,
                      unsigned long long* packed, int* rank, int e_cnt) {
    int e = blockIdx.x * blockDim.x + threadIdx.x;
    if (e < e_cnt) {
        int c = col_idx[e];
        unsigned int wfix = (unsigned int)(ew[e] * FIXED_SCALE + 0.5f);
        unsigned long long inc = (1ull << 32) | (unsigned long long)wfix;
        unsigned long long old = atomicAdd(&packed[c], inc);
        rank[e] = (int)(old >> 32);
    }
}

// block-sum of counts (hi32) + fused dis = rsqrt(1 + wsum) computation
__global__ void k_scan1(const unsigned long long* __restrict__ packed,
                        int* bsum, float* dis, int n) {
    __shared__ int s[256];
    int i = blockIdx.x * 256 + threadIdx.x;
    int cnt = 0;
    if (i < n) {
        unsigned long long p = packed[i];
        cnt = (int)(p >> 32);
        float wsum = (float)(unsigned int)(p & 0xffffffffull) * INV_FIXED_SCALE;
        dis[i] = rsqrtf(1.0f + wsum);   // self-loop weight 1 included
    }
    s[threadIdx.x] = cnt;
    __syncthreads();
    for (int off = 128; off > 0; off >>= 1) {
        if (threadIdx.x < off) s[threadIdx.x] += s[threadIdx.x + off];
        __syncthreads();
    }
    if (threadIdx.x == 0) bsum[blockIdx.x] = s[0];
}

__global__ void k_scan2(const int* __restrict__ bsum, int* boff, int nb) {
    __shared__ int s[256];
    int t = threadIdx.x;
    int v = (t < nb) ? bsum[t] : 0;
    s[t] = v;
    __syncthreads();
    for (int off = 1; off < 256; off <<= 1) {
        int x = (t >= off) ? s[t - off] : 0;
        __syncthreads();
        s[t] += x;
        __syncthreads();
    }
    if (t < nb) boff[t] = s[t] - v;  // exclusive
}

__global__ void k_scan3(const unsigned long long* __restrict__ packed,
                        const int* __restrict__ boff,
                        int* row_ptr, int n, int e_total) {
    __shared__ int s[256];
    int t = threadIdx.x;
    int i = blockIdx.x * 256 + t;
    int v = (i < n) ? (int)(packed[i] >> 32) : 0;
    s[t] = v;
    __syncthreads();
    for (int off = 1; off < 256; off <<= 1) {
        int x = (t >= off) ? s[t - off] : 0;
        __syncthreads();
        s[t] += x;
        __syncthreads();
    }
    int ex = s[t] - v + boff[blockIdx.x];
    if (i < n) row_ptr[i] = ex;
    if (i == 0) row_ptr[n] = e_total;
}

// atomic-free fill: slot = row_ptr[dest] + rank
__global__ void k_fill(const int* __restrict__ row_idx, const int* __restrict__ col_idx,
                       const float* __restrict__ ew, const float* __restrict__ dis,
                       const int* __restrict__ row_ptr, const int* __restrict__ rank,
                       int2* ep, int e_cnt) {
    int e = blockIdx.x * blockDim.x + threadIdx.x;
    if (e < e_cnt) {
        int r = row_idx[e];
        int c = col_idx[e];
        float nm = dis[r] * ew[e] * dis[c];
        int p = row_ptr[c] + rank[e];
        ep[p] = make_int2(r, __float_as_int(nm));
    }
}

// ---------------- dense transform: Y[n][f] = sum_k X[n][k] * W[f][k] ----------------
// 64-node tile in LDS; 8 waves x (F/8) features each.

template <int K, int F>
__global__ __launch_bounds__(512) void k_gemm(const float* __restrict__ X,
                                              const float* __restrict__ W,
                                              float* __restrict__ Y, int n) {
    constexpr int WAVES = 8;
    constexpr int FQ = F / WAVES;          // 12 (F=96) or 8 (F=64)
    constexpr int LK = K + 1;              // +1 pad: read aliasing 2-way = free
    __shared__ float xs[64 * LK];
    int n0 = blockIdx.x * 64;

    for (int idx = threadIdx.x; idx < 64 * K / 4; idx += 512) {
        int el = idx * 4;
        int nn = el / K, kk = el % K;
        float4 val;
        if (n0 + nn < n) val = *(const float4*)(X + (size_t)(n0 + nn) * K + kk);
        else             val = make_float4(0.f, 0.f, 0.f, 0.f);
        xs[nn * LK + kk + 0] = val.x;
        xs[nn * LK + kk + 1] = val.y;
        xs[nn * LK + kk + 2] = val.z;
        xs[nn * LK + kk + 3] = val.w;
    }
    __syncthreads();

    int lane_n = threadIdx.x & 63;
    int fbase = __builtin_amdgcn_readfirstlane((int)(threadIdx.x >> 6)) * FQ;
    const float* __restrict__ Wp = W + (size_t)fbase * K;

    float acc[FQ];
#pragma unroll
    for (int j = 0; j < FQ; ++j) acc[j] = 0.f;

#pragma unroll 4
    for (int k = 0; k < K; ++k) {
        float xv = xs[lane_n * LK + k];
#pragma unroll
        for (int j = 0; j < FQ; ++j) acc[j] = fmaf(Wp[j * K + k], xv, acc[j]);
    }

    int nn = n0 + lane_n;
    if (nn < n) {
        float* yp = Y + (size_t)nn * F + fbase;
#pragma unroll
        for (int j = 0; j < FQ; j += 4) {
            *(float4*)(yp + j) = make_float4(acc[j], acc[j + 1], acc[j + 2], acc[j + 3]);
        }
    }
}

// ---------------- aggregation: XCD-affine feature shards ----------------
// chunk = blockIdx.x & 7 (one feature shard per XCD under round-robin
// dispatch); thread = one node's whole shard (CF floats, NV float4s).

template <int F, bool BN>
__global__ __launch_bounds__(256) void k_aggr(
    const float* __restrict__ xw, const int* __restrict__ row_ptr,
    const int2* __restrict__ ep,
    const float* __restrict__ dis, const float* __restrict__ bias,
    const float* __restrict__ g, const float* __restrict__ beta,
    const float* __restrict__ m, const float* __restrict__ v,
    float* __restrict__ out, int n) {
    constexpr int CF = F / 8;      // floats per shard: 12 (F=96) or 8 (F=64)
    constexpr int NV = CF / 4;     // float4s per shard: 3 or 2
    int chunk = blockIdx.x & 7;
    int node = (blockIdx.x >> 3) * 256 + threadIdx.x;
    if (node >= n) return;
    int fb = chunk * CF;

    float d = dis[node];
    float d2 = d * d;
    const float4* selfp = (const float4*)(xw + (size_t)node * F + fb);
    float4 acc[NV];
#pragma unroll
    for (int j = 0; j < NV; ++j) {
        float4 s = selfp[j];
        acc[j] = make_float4(d2 * s.x, d2 * s.y, d2 * s.z, d2 * s.w);
    }

    int e0 = row_ptr[node], e1 = row_ptr[node + 1];
    int e = e0;
    for (; e + 2 <= e1; e += 2) {
        int2 p0 = ep[e + 0];
        int2 p1 = ep[e + 1];
        const float4* b0 = (const float4*)(xw + (size_t)p0.x * F + fb);
        const float4* b1 = (const float4*)(xw + (size_t)p1.x * F + fb);
        float4 t0[NV], t1[NV];
#pragma unroll
        for (int j = 0; j < NV; ++j) t0[j] = b0[j];
#pragma unroll
        for (int j = 0; j < NV; ++j) t1[j] = b1[j];
        float w0 = __int_as_float(p0.y);
        float w1 = __int_as_float(p1.y);
#pragma unroll
        for (int j = 0; j < NV; ++j) acc[j] = f4fma(w0, t0[j], acc[j]);
#pragma unroll
        for (int j = 0; j < NV; ++j) acc[j] = f4fma(w1, t1[j], acc[j]);
    }
    if (e < e1) {
        int2 p = ep[e];
        const float4* b0 = (const float4*)(xw + (size_t)p.x * F + fb);
        float w0 = __int_as_float(p.y);
#pragma unroll
        for (int j = 0; j < NV; ++j) acc[j] = f4fma(w0, b0[j], acc[j]);
    }

    const float4* bb = (const float4*)(bias + fb);
#pragma unroll
    for (int j = 0; j < NV; ++j) {
        float4 b = bb[j];
        acc[j].x += b.x; acc[j].y += b.y; acc[j].z += b.z; acc[j].w += b.w;
    }
    if (BN) {
        const float4* gp = (const float4*)(g + fb);
        const float4* bp = (const float4*)(beta + fb);
        const float4* mp = (const float4*)(m + fb);
        const float4* vp = (const float4*)(v + fb);
#pragma unroll
        for (int j = 0; j < NV; ++j) {
            float4 gm = gp[j], bt = bp[j], mm = mp[j], vv = vp[j];
            acc[j].x = fmaxf((acc[j].x - mm.x) * rsqrtf(vv.x + BN_EPS) * gm.x + bt.x, 0.f);
            acc[j].y = fmaxf((acc[j].y - mm.y) * rsqrtf(vv.y + BN_EPS) * gm.y + bt.y, 0.f);
            acc[j].z = fmaxf((acc[j].z - mm.z) * rsqrtf(vv.z + BN_EPS) * gm.z + bt.z, 0.f);
            acc[j].w = fmaxf((acc[j].w - mm.w) * rsqrtf(vv.w + BN_EPS) * gm.w + bt.w, 0.f);
        }
    }
    float4* op = (float4*)(out + (size_t)node * F + fb);
#pragma unroll
    for (int j = 0; j < NV; ++j) op[j] = acc[j];
}

// ---------------- launch ----------------

extern "C" void kernel_launch(void* const* d_in, const int* in_sizes, int n_in,
                              void* d_out, int out_size, void* d_ws, size_t ws_size,
                              hipStream_t stream) {
    constexpr int IN = 128, H = 96, OUT = 64;

    const float* x   = (const float*)d_in[0];
    const int*   ei  = (const int*)d_in[1];
    const float* ew  = (const float*)d_in[2];
    const float* W1  = (const float*)d_in[3];
    const float* b1  = (const float*)d_in[4];
    const float* W2  = (const float*)d_in[5];
    const float* b2  = (const float*)d_in[6];
    const float* W3  = (const float*)d_in[7];
    const float* b3  = (const float*)d_in[8];
    const float* g1  = (const float*)d_in[9];
    const float* be1 = (const float*)d_in[10];
    const float* m1  = (const float*)d_in[11];
    const float* v1  = (const float*)d_in[12];
    const float* g2  = (const float*)d_in[13];
    const float* be2 = (const float*)d_in[14];
    const float* m2  = (const float*)d_in[15];
    const float* v2  = (const float*)d_in[16];

    const int N = in_sizes[0] / IN;   // 50000
    const int E = in_sizes[2];        // 800000
    const int* row_idx = ei;
    const int* col_idx = ei + E;

    char* ws = (char*)d_ws;
    size_t off = 0;
    auto alloc = [&](size_t bytes) -> void* {
        void* p = ws + off;
        off = (off + bytes + 255) & ~(size_t)255;
        return p;
    };
    unsigned long long* packed = (unsigned long long*)alloc((size_t)N * 8);
    float* dis    = (float*)alloc((size_t)N * 4);
    int*   row_ptr= (int*)alloc((size_t)(N + 1) * 4);
    int*   bsum   = (int*)alloc(256 * 4);
    int*   boff   = (int*)alloc(256 * 4);
    int*   rank   = (int*)alloc((size_t)E * 4);
    int2*  ep     = (int2*)alloc((size_t)E * 8);
    float* bufA   = (float*)alloc((size_t)N * H * 4);
    float* bufB   = (float*)alloc((size_t)N * H * 4);
    (void)ws_size; (void)n_in; (void)out_size;

    const int NB = (N + 255) / 256;   // 196 (<= 256 required by k_scan2)

    k_init<<<NB, 256, 0, stream>>>(packed, N);
    k_deg<<<(E + 255) / 256, 256, 0, stream>>>(col_idx, ew, packed, rank, E);
    k_scan1<<<NB, 256, 0, stream>>>(packed, bsum, dis, N);
    k_scan2<<<1, 256, 0, stream>>>(bsum, boff, NB);
    k_scan3<<<NB, 256, 0, stream>>>(packed, boff, row_ptr, N, E);
    k_fill<<<(E + 255) / 256, 256, 0, stream>>>(row_idx, col_idx, ew, dis,
                                                row_ptr, rank, ep, E);

    const int GN = (N + 63) / 64;
    const int GA = 8 * NB;   // 8 feature shards x node-blocks

    // layer 1
    k_gemm<IN, H><<<GN, 512, 0, stream>>>(x, W1, bufA, N);
    k_aggr<H, true><<<GA, 256, 0, stream>>>(
        bufA, row_ptr, ep, dis, b1, g1, be1, m1, v1, bufB, N);

    // layer 2
    k_gemm<H, H><<<GN, 512, 0, stream>>>(bufB, W2, bufA, N);
    k_aggr<H, true><<<GA, 256, 0, stream>>>(
        bufA, row_ptr, ep, dis, b2, g2, be2, m2, v2, bufB, N);

    // layer 3
    k_gemm<H, OUT><<<GN, 512, 0, stream>>>(bufB, W3, bufA, N);
    k_aggr<OUT, false><<<GA, 256, 0, stream>>>(
        bufA, row_ptr, ep, dis, b3, nullptr, nullptr, nullptr, nullptr,
        (float*)d_out, N);
}

// Round 6
// 321.888 us; speedup vs baseline: 2.4166x; 2.4166x over previous
//
#include <hip/hip_runtime.h>
#include <hip/hip_fp16.h>

// GCN 3-layer: x -> GCNConv(W1)+BN+ReLU -> GCNConv(W2)+BN+ReLU -> GCNConv(W3)
// Dest-sorted CSR built once (1 u64 atomic/edge -> counts, weighted degree,
// in-bucket rank; atomic-free fill). Aggregation: gather with fp16-staged
// features (halves L2-fill bytes, the measured ~3TB/s bottleneck), fp32
// accumulate. Layout thread=(node, 16B chunk): consecutive lanes read one
// contiguous row -> fully coalesced (the R5 XCD-shard experiment broke this
// and quadrupled FETCH; reverted).

constexpr float BN_EPS = 1e-5f;
constexpr float FIXED_SCALE = 33554432.0f;        // 2^25
constexpr float INV_FIXED_SCALE = 1.0f / 33554432.0f;

// ---------------- graph build ----------------

__global__ void k_init(unsigned long long* packed, int n) {
    int i = blockIdx.x * blockDim.x + threadIdx.x;
    if (i < n) packed[i] = 0ull;
}

// one u64 atomic per edge; old>>32 = rank of this edge within its dest bucket
__global__ void k_deg(const int* __restrict__ col_idx, const float* __restrict__ ew,
                      unsigned long long* packed, int* rank, int e_cnt) {
    int e = blockIdx.x * blockDim.x + threadIdx.x;
    if (e < e_cnt) {
        int c = col_idx[e];
        unsigned int wfix = (unsigned int)(ew[e] * FIXED_SCALE + 0.5f);
        unsigned long long inc = (1ull << 32) | (unsigned long long)wfix;
        unsigned long long old = atomicAdd(&packed[c], inc);
        rank[e] = (int)(old >> 32);
    }
}

// block-sum of counts (hi32) + fused dis = rsqrt(1 + wsum)
__global__ void k_scan1(const unsigned long long* __restrict__ packed,
                        int* bsum, float* dis, int n) {
    __shared__ int s[256];
    int i = blockIdx.x * 256 + threadIdx.x;
    int cnt = 0;
    if (i < n) {
        unsigned long long p = packed[i];
        cnt = (int)(p >> 32);
        float wsum = (float)(unsigned int)(p & 0xffffffffull) * INV_FIXED_SCALE;
        dis[i] = rsqrtf(1.0f + wsum);   // self-loop weight 1 included
    }
    s[threadIdx.x] = cnt;
    __syncthreads();
    for (int off = 128; off > 0; off >>= 1) {
        if (threadIdx.x < off) s[threadIdx.x] += s[threadIdx.x + off];
        __syncthreads();
    }
    if (threadIdx.x == 0) bsum[blockIdx.x] = s[0];
}

__global__ void k_scan2(const int* __restrict__ bsum, int* boff, int nb) {
    __shared__ int s[256];
    int t = threadIdx.x;
    int v = (t < nb) ? bsum[t] : 0;
    s[t] = v;
    __syncthreads();
    for (int off = 1; off < 256; off <<= 1) {
        int x = (t >= off) ? s[t - off] : 0;
        __syncthreads();
        s[t] += x;
        __syncthreads();
    }
    if (t < nb) boff[t] = s[t] - v;  // exclusive
}

__global__ void k_scan3(const unsigned long long* __restrict__ packed,
                        const int* __restrict__ boff,
                        int* row_ptr, int n, int e_total) {
    __shared__ int s[256];
    int t = threadIdx.x;
    int i = blockIdx.x * 256 + t;
    int v = (i < n) ? (int)(packed[i] >> 32) : 0;
    s[t] = v;
    __syncthreads();
    for (int off = 1; off < 256; off <<= 1) {
        int x = (t >= off) ? s[t - off] : 0;
        __syncthreads();
        s[t] += x;
        __syncthreads();
    }
    int ex = s[t] - v + boff[blockIdx.x];
    if (i < n) row_ptr[i] = ex;
    if (i == 0) row_ptr[n] = e_total;
}

// atomic-free fill: slot = row_ptr[dest] + rank
__global__ void k_fill(const int* __restrict__ row_idx, const int* __restrict__ col_idx,
                       const float* __restrict__ ew, const float* __restrict__ dis,
                       const int* __restrict__ row_ptr, const int* __restrict__ rank,
                       int2* ep, int e_cnt) {
    int e = blockIdx.x * blockDim.x + threadIdx.x;
    if (e < e_cnt) {
        int r = row_idx[e];
        int c = col_idx[e];
        float nm = dis[r] * ew[e] * dis[c];
        int p = row_ptr[c] + rank[e];
        ep[p] = make_int2(r, __float_as_int(nm));
    }
}

// ---------------- dense transform: Y[n][f] = sum_k X[n][k] * W[f][k] ----------------
// 64-node LDS tile; 8 waves x (F/8) features each; fp16 output for aggregation.

template <int K, int F>
__global__ __launch_bounds__(512) void k_gemm(const float* __restrict__ X,
                                              const float* __restrict__ W,
                                              __half* __restrict__ Y, int n) {
    constexpr int WAVES = 8;
    constexpr int FQ = F / WAVES;          // 12 (F=96) or 8 (F=64)
    constexpr int LK = K + 1;              // +1 pad: 2-way read aliasing = free
    __shared__ float xs[64 * LK];
    int n0 = blockIdx.x * 64;

    for (int idx = threadIdx.x; idx < 64 * K / 4; idx += 512) {
        int el = idx * 4;
        int nn = el / K, kk = el % K;
        float4 val;
        if (n0 + nn < n) val = *(const float4*)(X + (size_t)(n0 + nn) * K + kk);
        else             val = make_float4(0.f, 0.f, 0.f, 0.f);
        xs[nn * LK + kk + 0] = val.x;
        xs[nn * LK + kk + 1] = val.y;
        xs[nn * LK + kk + 2] = val.z;
        xs[nn * LK + kk + 3] = val.w;
    }
    __syncthreads();

    int lane_n = threadIdx.x & 63;
    int fbase = __builtin_amdgcn_readfirstlane((int)(threadIdx.x >> 6)) * FQ;
    const float* __restrict__ Wp = W + (size_t)fbase * K;

    float acc[FQ];
#pragma unroll
    for (int j = 0; j < FQ; ++j) acc[j] = 0.f;

#pragma unroll 4
    for (int k = 0; k < K; ++k) {
        float xv = xs[lane_n * LK + k];
#pragma unroll
        for (int j = 0; j < FQ; ++j) acc[j] = fmaf(Wp[j * K + k], xv, acc[j]);
    }

    int nn = n0 + lane_n;
    if (nn < n) {
        __half2* yp = (__half2*)(Y + (size_t)nn * F + fbase);   // fbase even
#pragma unroll
        for (int j = 0; j < FQ / 2; ++j)
            yp[j] = __floats2half2_rn(acc[2 * j], acc[2 * j + 1]);
    }
}

// ---------------- aggregation (gather fp16, accumulate fp32) ----------------
// thread = (node, 8-half chunk); 16B loads, consecutive lanes cover one row.

__device__ inline void h8_acc(uint4 u, float w, float acc[8]) {
    float2 a = __half22float2(*(const __half2*)&u.x);
    float2 b = __half22float2(*(const __half2*)&u.y);
    float2 c = __half22float2(*(const __half2*)&u.z);
    float2 d = __half22float2(*(const __half2*)&u.w);
    acc[0] = fmaf(w, a.x, acc[0]); acc[1] = fmaf(w, a.y, acc[1]);
    acc[2] = fmaf(w, b.x, acc[2]); acc[3] = fmaf(w, b.y, acc[3]);
    acc[4] = fmaf(w, c.x, acc[4]); acc[5] = fmaf(w, c.y, acc[5]);
    acc[6] = fmaf(w, d.x, acc[6]); acc[7] = fmaf(w, d.y, acc[7]);
}

template <int F, bool BN>
__global__ __launch_bounds__(256) void k_aggr(
    const __half* __restrict__ xw, const int* __restrict__ row_ptr,
    const int2* __restrict__ ep,
    const float* __restrict__ dis, const float* __restrict__ bias,
    const float* __restrict__ g, const float* __restrict__ beta,
    const float* __restrict__ m, const float* __restrict__ v,
    float* __restrict__ out, int n) {
    constexpr int FQ = F / 8;      // 16B chunks per row: 12 (F=96) or 8 (F=64)
    int tg = blockIdx.x * 256 + threadIdx.x;
    int node = tg / FQ;
    int q = tg - node * FQ;
    if (node >= n) return;

    const uint4* __restrict__ base = (const uint4*)xw;   // row = FQ uint4s

    float acc[8];
    {
        float d = dis[node];
        float d2 = d * d;
        uint4 sv = base[(size_t)node * FQ + q];
        float2 a = __half22float2(*(const __half2*)&sv.x);
        float2 b = __half22float2(*(const __half2*)&sv.y);
        float2 c = __half22float2(*(const __half2*)&sv.z);
        float2 dd = __half22float2(*(const __half2*)&sv.w);
        acc[0] = d2 * a.x; acc[1] = d2 * a.y;
        acc[2] = d2 * b.x; acc[3] = d2 * b.y;
        acc[4] = d2 * c.x; acc[5] = d2 * c.y;
        acc[6] = d2 * dd.x; acc[7] = d2 * dd.y;
    }

    int e0 = row_ptr[node], e1 = row_ptr[node + 1];
    int e = e0;
    for (; e + 4 <= e1; e += 4) {
        int2 p0 = ep[e + 0];
        int2 p1 = ep[e + 1];
        int2 p2 = ep[e + 2];
        int2 p3 = ep[e + 3];
        uint4 x0 = base[(size_t)p0.x * FQ + q];
        uint4 x1 = base[(size_t)p1.x * FQ + q];
        uint4 x2 = base[(size_t)p2.x * FQ + q];
        uint4 x3 = base[(size_t)p3.x * FQ + q];
        h8_acc(x0, __int_as_float(p0.y), acc);
        h8_acc(x1, __int_as_float(p1.y), acc);
        h8_acc(x2, __int_as_float(p2.y), acc);
        h8_acc(x3, __int_as_float(p3.y), acc);
    }
    for (; e < e1; ++e) {
        int2 p = ep[e];
        uint4 xv = base[(size_t)p.x * FQ + q];
        h8_acc(xv, __int_as_float(p.y), acc);
    }

    int fb = q * 8;
    const float4* bb = (const float4*)(bias + fb);
    float4 b0 = bb[0], b1 = bb[1];
    acc[0] += b0.x; acc[1] += b0.y; acc[2] += b0.z; acc[3] += b0.w;
    acc[4] += b1.x; acc[5] += b1.y; acc[6] += b1.z; acc[7] += b1.w;
    if (BN) {
        const float* gp = g + fb;
        const float* bp = beta + fb;
        const float* mp = m + fb;
        const float* vp = v + fb;
#pragma unroll
        for (int j = 0; j < 8; ++j) {
            acc[j] = fmaxf((acc[j] - mp[j]) * rsqrtf(vp[j] + BN_EPS) * gp[j] + bp[j], 0.f);
        }
    }
    float4* op = (float4*)(out + (size_t)node * F + fb);
    op[0] = make_float4(acc[0], acc[1], acc[2], acc[3]);
    op[1] = make_float4(acc[4], acc[5], acc[6], acc[7]);
}

// ---------------- launch ----------------

extern "C" void kernel_launch(void* const* d_in, const int* in_sizes, int n_in,
                              void* d_out, int out_size, void* d_ws, size_t ws_size,
                              hipStream_t stream) {
    constexpr int IN = 128, H = 96, OUT = 64;

    const float* x   = (const float*)d_in[0];
    const int*   ei  = (const int*)d_in[1];
    const float* ew  = (const float*)d_in[2];
    const float* W1  = (const float*)d_in[3];
    const float* b1  = (const float*)d_in[4];
    const float* W2  = (const float*)d_in[5];
    const float* b2  = (const float*)d_in[6];
    const float* W3  = (const float*)d_in[7];
    const float* b3  = (const float*)d_in[8];
    const float* g1  = (const float*)d_in[9];
    const float* be1 = (const float*)d_in[10];
    const float* m1  = (const float*)d_in[11];
    const float* v1  = (const float*)d_in[12];
    const float* g2  = (const float*)d_in[13];
    const float* be2 = (const float*)d_in[14];
    const float* m2  = (const float*)d_in[15];
    const float* v2  = (const float*)d_in[16];

    const int N = in_sizes[0] / IN;   // 50000
    const int E = in_sizes[2];        // 800000
    const int* row_idx = ei;
    const int* col_idx = ei + E;

    char* ws = (char*)d_ws;
    size_t off = 0;
    auto alloc = [&](size_t bytes) -> void* {
        void* p = ws + off;
        off = (off + bytes + 255) & ~(size_t)255;
        return p;
    };
    unsigned long long* packed = (unsigned long long*)alloc((size_t)N * 8);
    float*  dis     = (float*)alloc((size_t)N * 4);
    int*    row_ptr = (int*)alloc((size_t)(N + 1) * 4);
    int*    bsum    = (int*)alloc(256 * 4);
    int*    boff    = (int*)alloc(256 * 4);
    int*    rank    = (int*)alloc((size_t)E * 4);
    int2*   ep      = (int2*)alloc((size_t)E * 8);
    __half* bufH    = (__half*)alloc((size_t)N * H * 2);   // fp16 gemm out
    float*  bufF    = (float*)alloc((size_t)N * H * 4);    // fp32 aggr out
    (void)ws_size; (void)n_in; (void)out_size;

    const int NB = (N + 255) / 256;   // 196 (<= 256 required by k_scan2)

    k_init<<<NB, 256, 0, stream>>>(packed, N);
    k_deg<<<(E + 255) / 256, 256, 0, stream>>>(col_idx, ew, packed, rank, E);
    k_scan1<<<NB, 256, 0, stream>>>(packed, bsum, dis, N);
    k_scan2<<<1, 256, 0, stream>>>(bsum, boff, NB);
    k_scan3<<<NB, 256, 0, stream>>>(packed, boff, row_ptr, N, E);
    k_fill<<<(E + 255) / 256, 256, 0, stream>>>(row_idx, col_idx, ew, dis,
                                                row_ptr, rank, ep, E);

    const int GN = (N + 63) / 64;
    const int GA96 = ((size_t)N * (H / 8) + 255) / 256;
    const int GA64 = ((size_t)N * (OUT / 8) + 255) / 256;

    // layer 1
    k_gemm<IN, H><<<GN, 512, 0, stream>>>(x, W1, bufH, N);
    k_aggr<H, true><<<GA96, 256, 0, stream>>>(
        bufH, row_ptr, ep, dis, b1, g1, be1, m1, v1, bufF, N);

    // layer 2
    k_gemm<H, H><<<GN, 512, 0, stream>>>(bufF, W2, bufH, N);
    k_aggr<H, true><<<GA96, 256, 0, stream>>>(
        bufH, row_ptr, ep, dis, b2, g2, be2, m2, v2, bufF, N);

    // layer 3
    k_gemm<H, OUT><<<GN, 512, 0, stream>>>(bufF, W3, bufH, N);
    k_aggr<OUT, false><<<GA64, 256, 0, stream>>>(
        bufH, row_ptr, ep, dis, b3, nullptr, nullptr, nullptr, nullptr,
        (float*)d_out, N);
}

// Round 7
// 286.147 us; speedup vs baseline: 2.7184x; 1.1249x over previous
//
#include <hip/hip_runtime.h>
#include <hip/hip_fp16.h>

// GCN 3-layer: x -> GCNConv(W1)+BN+ReLU -> GCNConv(W2)+BN+ReLU -> GCNConv(W3)
// Dest-sorted CSR built once (1 u64 atomic/edge -> counts, weighted degree,
// in-bucket rank; atomic-free fill).
// Dense transforms: MFMA f16 (16x16x32), one wave = 16 nodes x all F features,
// A/B frags loaded directly from global (16B/lane contiguous), fp32 accum.
// Aggregation: fp16 gather (L2-fill-path bound ~3TB/s measured), fp32 accum,
// fp16 out for layers 1-2 (feeds next GEMM), fp32 out for the final layer.

constexpr float BN_EPS = 1e-5f;
constexpr float FIXED_SCALE = 33554432.0f;        // 2^25
constexpr float INV_FIXED_SCALE = 1.0f / 33554432.0f;

typedef _Float16 f16x8 __attribute__((ext_vector_type(8)));
typedef float f32x4 __attribute__((ext_vector_type(4)));

// ---------------- graph build ----------------

__global__ void k_init(unsigned long long* packed, int n) {
    int i = blockIdx.x * blockDim.x + threadIdx.x;
    if (i < n) packed[i] = 0ull;
}

// one u64 atomic per edge; old>>32 = rank of this edge within its dest bucket
__global__ void k_deg(const int* __restrict__ col_idx, const float* __restrict__ ew,
                      unsigned long long* packed, int* rank, int e_cnt) {
    int e = blockIdx.x * blockDim.x + threadIdx.x;
    if (e < e_cnt) {
        int c = col_idx[e];
        unsigned int wfix = (unsigned int)(ew[e] * FIXED_SCALE + 0.5f);
        unsigned long long inc = (1ull << 32) | (unsigned long long)wfix;
        unsigned long long old = atomicAdd(&packed[c], inc);
        rank[e] = (int)(old >> 32);
    }
}

// block-sum of counts (hi32) + fused dis = rsqrt(1 + wsum)
__global__ void k_scan1(const unsigned long long* __restrict__ packed,
                        int* bsum, float* dis, int n) {
    __shared__ int s[256];
    int i = blockIdx.x * 256 + threadIdx.x;
    int cnt = 0;
    if (i < n) {
        unsigned long long p = packed[i];
        cnt = (int)(p >> 32);
        float wsum = (float)(unsigned int)(p & 0xffffffffull) * INV_FIXED_SCALE;
        dis[i] = rsqrtf(1.0f + wsum);   // self-loop weight 1 included
    }
    s[threadIdx.x] = cnt;
    __syncthreads();
    for (int off = 128; off > 0; off >>= 1) {
        if (threadIdx.x < off) s[threadIdx.x] += s[threadIdx.x + off];
        __syncthreads();
    }
    if (threadIdx.x == 0) bsum[blockIdx.x] = s[0];
}

__global__ void k_scan2(const int* __restrict__ bsum, int* boff, int nb) {
    __shared__ int s[256];
    int t = threadIdx.x;
    int v = (t < nb) ? bsum[t] : 0;
    s[t] = v;
    __syncthreads();
    for (int off = 1; off < 256; off <<= 1) {
        int x = (t >= off) ? s[t - off] : 0;
        __syncthreads();
        s[t] += x;
        __syncthreads();
    }
    if (t < nb) boff[t] = s[t] - v;  // exclusive
}

__global__ void k_scan3(const unsigned long long* __restrict__ packed,
                        const int* __restrict__ boff,
                        int* row_ptr, int n, int e_total) {
    __shared__ int s[256];
    int t = threadIdx.x;
    int i = blockIdx.x * 256 + t;
    int v = (i < n) ? (int)(packed[i] >> 32) : 0;
    s[t] = v;
    __syncthreads();
    for (int off = 1; off < 256; off <<= 1) {
        int x = (t >= off) ? s[t - off] : 0;
        __syncthreads();
        s[t] += x;
        __syncthreads();
    }
    int ex = s[t] - v + boff[blockIdx.x];
    if (i < n) row_ptr[i] = ex;
    if (i == 0) row_ptr[n] = e_total;
}

// atomic-free fill: slot = row_ptr[dest] + rank
__global__ void k_fill(const int* __restrict__ row_idx, const int* __restrict__ col_idx,
                       const float* __restrict__ ew, const float* __restrict__ dis,
                       const int* __restrict__ row_ptr, const int* __restrict__ rank,
                       int2* ep, int e_cnt) {
    int e = blockIdx.x * blockDim.x + threadIdx.x;
    if (e < e_cnt) {
        int r = row_idx[e];
        int c = col_idx[e];
        float nm = dis[r] * ew[e] * dis[c];
        int p = row_ptr[c] + rank[e];
        ep[p] = make_int2(r, __float_as_int(nm));
    }
}

// ---------------- fp32 -> fp16 conversion (x and W, once) ----------------

__global__ void k_cvt(const float* __restrict__ src, _Float16* __restrict__ dst,
                      int cnt4) {   // cnt in float4 units
    int i = blockIdx.x * blockDim.x + threadIdx.x;
    if (i < cnt4) {
        float4 v = *(const float4*)(src + i * 4);
        __half2 h0 = __floats2half2_rn(v.x, v.y);
        __half2 h1 = __floats2half2_rn(v.z, v.w);
        uint2 u = make_uint2(*(unsigned int*)&h0, *(unsigned int*)&h1);
        *(uint2*)(dst + (size_t)i * 4) = u;
    }
}

// ---------------- dense transform via MFMA f16 ----------------
// Y[n][f] = sum_k X[n][k] * W[f][k]; one wave = 16 nodes x F features.
// A-frag: lane loads X[n0 + (lane&15)][kt*32 + (lane>>4)*8 ..+7] (16B).
// B-frag: lane loads W[ft*16 + (lane&15)][kt*32 + (lane>>4)*8 ..+7] (16B).
// C/D: col = lane&15 (feature), row = (lane>>4)*4 + reg (node).

template <int K, int F>
__global__ __launch_bounds__(256) void k_gemm_mfma(const _Float16* __restrict__ X,
                                                   const _Float16* __restrict__ Wh,
                                                   _Float16* __restrict__ Y, int n) {
    constexpr int KT = K / 32;   // 4 (K=128) or 3 (K=96)
    constexpr int FT = F / 16;   // 6 (F=96) or 4 (F=64)
    int wave = threadIdx.x >> 6;
    int lane = threadIdx.x & 63;
    int n0 = (blockIdx.x * 4 + wave) * 16;
    if (n0 >= n) return;
    int quad = lane >> 4;
    int r = lane & 15;

    const f16x8* __restrict__ xrow =
        (const f16x8*)(X + (size_t)(n0 + r) * K + quad * 8);
    f16x8 a[KT];
#pragma unroll
    for (int kt = 0; kt < KT; ++kt) a[kt] = xrow[kt * 4];   // kt*32 halves

    const f16x8* __restrict__ wrow =
        (const f16x8*)(Wh + (size_t)r * K + quad * 8);

    f32x4 acc[FT];
#pragma unroll
    for (int ft = 0; ft < FT; ++ft) acc[ft] = (f32x4){0.f, 0.f, 0.f, 0.f};

#pragma unroll
    for (int kt = 0; kt < KT; ++kt) {
#pragma unroll
        for (int ft = 0; ft < FT; ++ft) {
            f16x8 b = wrow[(size_t)ft * 2 * K + kt * 4];   // (ft*16*K + kt*32) halves
            acc[ft] = __builtin_amdgcn_mfma_f32_16x16x32_f16(a[kt], b, acc[ft], 0, 0, 0);
        }
    }

#pragma unroll
    for (int ft = 0; ft < FT; ++ft) {
#pragma unroll
        for (int reg = 0; reg < 4; ++reg) {
            int row = n0 + quad * 4 + reg;
            Y[(size_t)row * F + ft * 16 + r] = (_Float16)acc[ft][reg];
        }
    }
}

// ---------------- aggregation (gather fp16, accumulate fp32) ----------------
// thread = (node, 8-half chunk); 16B loads, consecutive lanes cover one row.

__device__ inline void h8_acc(uint4 u, float w, float acc[8]) {
    float2 a = __half22float2(*(const __half2*)&u.x);
    float2 b = __half22float2(*(const __half2*)&u.y);
    float2 c = __half22float2(*(const __half2*)&u.z);
    float2 d = __half22float2(*(const __half2*)&u.w);
    acc[0] = fmaf(w, a.x, acc[0]); acc[1] = fmaf(w, a.y, acc[1]);
    acc[2] = fmaf(w, b.x, acc[2]); acc[3] = fmaf(w, b.y, acc[3]);
    acc[4] = fmaf(w, c.x, acc[4]); acc[5] = fmaf(w, c.y, acc[5]);
    acc[6] = fmaf(w, d.x, acc[6]); acc[7] = fmaf(w, d.y, acc[7]);
}

template <int F, bool BN, bool HOUT>
__global__ __launch_bounds__(256) void k_aggr(
    const _Float16* __restrict__ xw, const int* __restrict__ row_ptr,
    const int2* __restrict__ ep,
    const float* __restrict__ dis, const float* __restrict__ bias,
    const float* __restrict__ g, const float* __restrict__ beta,
    const float* __restrict__ m, const float* __restrict__ v,
    void* __restrict__ out, int n) {
    constexpr int FQ = F / 8;      // 16B chunks per row: 12 (F=96) or 8 (F=64)
    int tg = blockIdx.x * 256 + threadIdx.x;
    int node = tg / FQ;
    int q = tg - node * FQ;
    if (node >= n) return;

    const uint4* __restrict__ base = (const uint4*)xw;   // row = FQ uint4s

    float acc[8];
    {
        float d = dis[node];
        float d2 = d * d;
        uint4 sv = base[(size_t)node * FQ + q];
        float2 a = __half22float2(*(const __half2*)&sv.x);
        float2 b = __half22float2(*(const __half2*)&sv.y);
        float2 c = __half22float2(*(const __half2*)&sv.z);
        float2 dd = __half22float2(*(const __half2*)&sv.w);
        acc[0] = d2 * a.x; acc[1] = d2 * a.y;
        acc[2] = d2 * b.x; acc[3] = d2 * b.y;
        acc[4] = d2 * c.x; acc[5] = d2 * c.y;
        acc[6] = d2 * dd.x; acc[7] = d2 * dd.y;
    }

    int e0 = row_ptr[node], e1 = row_ptr[node + 1];
    int e = e0;
    for (; e + 4 <= e1; e += 4) {
        int2 p0 = ep[e + 0];
        int2 p1 = ep[e + 1];
        int2 p2 = ep[e + 2];
        int2 p3 = ep[e + 3];
        uint4 x0 = base[(size_t)p0.x * FQ + q];
        uint4 x1 = base[(size_t)p1.x * FQ + q];
        uint4 x2 = base[(size_t)p2.x * FQ + q];
        uint4 x3 = base[(size_t)p3.x * FQ + q];
        h8_acc(x0, __int_as_float(p0.y), acc);
        h8_acc(x1, __int_as_float(p1.y), acc);
        h8_acc(x2, __int_as_float(p2.y), acc);
        h8_acc(x3, __int_as_float(p3.y), acc);
    }
    for (; e < e1; ++e) {
        int2 p = ep[e];
        uint4 xv = base[(size_t)p.x * FQ + q];
        h8_acc(xv, __int_as_float(p.y), acc);
    }

    int fb = q * 8;
    const float4* bb = (const float4*)(bias + fb);
    float4 b0 = bb[0], b1 = bb[1];
    acc[0] += b0.x; acc[1] += b0.y; acc[2] += b0.z; acc[3] += b0.w;
    acc[4] += b1.x; acc[5] += b1.y; acc[6] += b1.z; acc[7] += b1.w;
    if (BN) {
        const float* gp = g + fb;
        const float* bp = beta + fb;
        const float* mp = m + fb;
        const float* vp = v + fb;
#pragma unroll
        for (int j = 0; j < 8; ++j) {
            acc[j] = fmaxf((acc[j] - mp[j]) * rsqrtf(vp[j] + BN_EPS) * gp[j] + bp[j], 0.f);
        }
    }
    if (HOUT) {
        __half2 h0 = __floats2half2_rn(acc[0], acc[1]);
        __half2 h1 = __floats2half2_rn(acc[2], acc[3]);
        __half2 h2 = __floats2half2_rn(acc[4], acc[5]);
        __half2 h3 = __floats2half2_rn(acc[6], acc[7]);
        uint4 u = make_uint4(*(unsigned int*)&h0, *(unsigned int*)&h1,
                             *(unsigned int*)&h2, *(unsigned int*)&h3);
        ((uint4*)out)[(size_t)node * FQ + q] = u;
    } else {
        float4* op = (float4*)((float*)out + (size_t)node * F + fb);
        op[0] = make_float4(acc[0], acc[1], acc[2], acc[3]);
        op[1] = make_float4(acc[4], acc[5], acc[6], acc[7]);
    }
}

// ---------------- launch ----------------

extern "C" void kernel_launch(void* const* d_in, const int* in_sizes, int n_in,
                              void* d_out, int out_size, void* d_ws, size_t ws_size,
                              hipStream_t stream) {
    constexpr int IN = 128, H = 96, OUT = 64;

    const float* x   = (const float*)d_in[0];
    const int*   ei  = (const int*)d_in[1];
    const float* ew  = (const float*)d_in[2];
    const float* W1  = (const float*)d_in[3];
    const float* b1  = (const float*)d_in[4];
    const float* W2  = (const float*)d_in[5];
    const float* b2  = (const float*)d_in[6];
    const float* W3  = (const float*)d_in[7];
    const float* b3  = (const float*)d_in[8];
    const float* g1  = (const float*)d_in[9];
    const float* be1 = (const float*)d_in[10];
    const float* m1  = (const float*)d_in[11];
    const float* v1  = (const float*)d_in[12];
    const float* g2  = (const float*)d_in[13];
    const float* be2 = (const float*)d_in[14];
    const float* m2  = (const float*)d_in[15];
    const float* v2  = (const float*)d_in[16];

    const int N = in_sizes[0] / IN;   // 50000
    const int E = in_sizes[2];        // 800000
    const int* row_idx = ei;
    const int* col_idx = ei + E;

    char* ws = (char*)d_ws;
    size_t off = 0;
    auto alloc = [&](size_t bytes) -> void* {
        void* p = ws + off;
        off = (off + bytes + 255) & ~(size_t)255;
        return p;
    };
    unsigned long long* packed = (unsigned long long*)alloc((size_t)N * 8);
    float*     dis     = (float*)alloc((size_t)N * 4);
    int*       row_ptr = (int*)alloc((size_t)(N + 1) * 4);
    int*       bsum    = (int*)alloc(256 * 4);
    int*       boff    = (int*)alloc(256 * 4);
    int*       rank    = (int*)alloc((size_t)E * 4);
    int2*      ep      = (int2*)alloc((size_t)E * 8);
    _Float16*  xh      = (_Float16*)alloc((size_t)N * IN * 2);
    _Float16*  w1h     = (_Float16*)alloc((size_t)H * IN * 2);
    _Float16*  w2h     = (_Float16*)alloc((size_t)H * H * 2);
    _Float16*  w3h     = (_Float16*)alloc((size_t)OUT * H * 2);
    _Float16*  bufA    = (_Float16*)alloc((size_t)N * H * 2);   // gemm out
    _Float16*  bufB    = (_Float16*)alloc((size_t)N * H * 2);   // aggr out
    (void)ws_size; (void)n_in; (void)out_size;

    const int NB = (N + 255) / 256;   // 196 (<= 256 required by k_scan2)

    k_init<<<NB, 256, 0, stream>>>(packed, N);
    k_deg<<<(E + 255) / 256, 256, 0, stream>>>(col_idx, ew, packed, rank, E);
    k_scan1<<<NB, 256, 0, stream>>>(packed, bsum, dis, N);
    k_scan2<<<1, 256, 0, stream>>>(bsum, boff, NB);
    k_scan3<<<NB, 256, 0, stream>>>(packed, boff, row_ptr, N, E);
    k_fill<<<(E + 255) / 256, 256, 0, stream>>>(row_idx, col_idx, ew, dis,
                                                row_ptr, rank, ep, E);

    // fp16 conversions (x + weights)
    k_cvt<<<(N * IN / 4 + 255) / 256, 256, 0, stream>>>(x, xh, N * IN / 4);
    k_cvt<<<(H * IN / 4 + 255) / 256, 256, 0, stream>>>(W1, w1h, H * IN / 4);
    k_cvt<<<(H * H / 4 + 255) / 256, 256, 0, stream>>>(W2, w2h, H * H / 4);
    k_cvt<<<(OUT * H / 4 + 255) / 256, 256, 0, stream>>>(W3, w3h, OUT * H / 4);

    const int GG = (N / 16 + 3) / 4;   // 4 waves/block, 16 nodes/wave
    const int GA96 = ((size_t)N * (H / 8) + 255) / 256;
    const int GA64 = ((size_t)N * (OUT / 8) + 255) / 256;

    // layer 1
    k_gemm_mfma<IN, H><<<GG, 256, 0, stream>>>(xh, w1h, bufA, N);
    k_aggr<H, true, true><<<GA96, 256, 0, stream>>>(
        bufA, row_ptr, ep, dis, b1, g1, be1, m1, v1, bufB, N);

    // layer 2
    k_gemm_mfma<H, H><<<GG, 256, 0, stream>>>(bufB, w2h, bufA, N);
    k_aggr<H, true, true><<<GA96, 256, 0, stream>>>(
        bufA, row_ptr, ep, dis, b2, g2, be2, m2, v2, bufB, N);

    // layer 3
    k_gemm_mfma<H, OUT><<<GG, 256, 0, stream>>>(bufB, w3h, bufA, N);
    k_aggr<OUT, false, false><<<GA64, 256, 0, stream>>>(
        bufA, row_ptr, ep, dis, b3, nullptr, nullptr, nullptr, nullptr,
        d_out, N);
}